// Round 7
// baseline (291.801 us; speedup 1.0000x reference)
//
#include <hip/hip_runtime.h>
#include <hip/hip_bf16.h>
#include <math.h>

#define DEV __device__ __forceinline__

constexpr int B=8, C=64, DIM=256, HID=128, S=64, NH=16, HD=4, LPIX=784;
constexpr int NPIX = B*LPIX;          // 6272
constexpr int CH   = (NPIX+255)/256;  // 25
constexpr int QB   = 12*((NPIX+511)/512); // 156 qkv blocks (12 groups x 13 chunks)

constexpr size_t OFF_X1O = 0;
constexpr size_t OFF_T1  = OFF_X1O + (size_t)B*C*LPIX;
constexpr size_t OFF_T2  = OFF_T1  + (size_t)B*HID*LPIX;
constexpr size_t OFF_XA  = OFF_T2  + (size_t)B*C*LPIX;
constexpr size_t OFF_BC2 = OFF_XA  + (size_t)B*DIM*LPIX;
constexpr size_t OFF_WGT = OFF_BC2 + (size_t)B*192*LPIX;        // B*S*L (pure softmax probs)
constexpr size_t OFF_H   = OFF_WGT + (size_t)B*S*LPIX;          // 4 * B*C*S
constexpr size_t OFF_HO  = OFF_H   + (size_t)4*B*C*S;
constexpr size_t OFF_QKV = OFF_HO  + (size_t)B*C*S;
constexpr size_t OFF_O   = OFF_QKV + (size_t)3*B*NH*LPIX*HD;    // 4 * B*L*C partials
constexpr size_t OFF_LS  = OFF_O   + (size_t)4*B*LPIX*C;        // 4 * B*NH*L
constexpr size_t OFF_MID = OFF_LS  + (size_t)4*B*NH*LPIX;

DEV float bnorm(float x, const float* p, int c, int nc){
  float g=p[c], bb=p[nc+c], m=p[2*nc+c], v=p[3*nc+c];
  return (x-m)*(g*rsqrtf(v+1e-5f))+bb;
}
DEV int refl(int p){ int k=p-1; if(k<0)k=-k; if(k>27)k=54-k; return k; }

DEV bool upix(int blk, int tid, int ngroups, int& grp, int& b, int& l){
  grp = blk % ngroups;
  int gidx = (blk/ngroups)*256 + tid;
  if(gidx >= NPIX) return false;
  b = gidx / LPIX; l = gidx % LPIX;
  return true;
}

// ================= bodies =================
// dw1t: zero-padded 34x34 LDS tile -> straight-line 7x7 conv (no bounds branches)
DEV void body_dw1t(int bc, int tid, float* xs, const float* X, const float* w, const float* bias, const float* bnp, float* out){
  int c = bc & 63, b = bc >> 6;
  const float* xp = X + ((size_t)(b*DIM+c))*LPIX;
  for(int i=tid;i<34*34;i+=256) xs[i]=0.f;
  __syncthreads();
  for(int i=tid;i<LPIX;i+=256){ int y=i/28, x=i%28; xs[(y+3)*34+(x+3)]=xp[i]; }
  __syncthreads();
  const float* wc = w + (size_t)c*49;
  float bs = bias[c];
  for(int i=tid;i<LPIX;i+=256){
    int y=i/28, x=i%28;
    float s = bs;
    #pragma unroll
    for(int ky=0;ky<7;ky++){
      #pragma unroll
      for(int kx=0;kx<7;kx++)
        s += xs[(y+ky)*34 + x+kx]*wc[ky*7+kx];
    }
    out[((size_t)(b*C+c))*LPIX + i] = bnorm(s,bnp,c,C);
  }
}

DEV void body_branch2(int bc, int tid, float* smem, const float* X,
                      const float* h1w,const float* v1w,const float* h2w,const float* v2w,
                      const float* bnp, float* xa){
  int c = bc & 63, b = bc >> 6;
  float* xs  = smem;
  float* mp  = smem+LPIX;
  float* xt  = smem+2*LPIX;
  float* attv= smem+2*LPIX+100;
  const float* xp = X + ((size_t)(b*DIM+64+c))*LPIX;
  for(int i=tid;i<LPIX;i+=256) xs[i]=xp[i];
  __syncthreads();
  for(int i=tid;i<LPIX;i+=256){
    int y=i/28, x=i%28;
    float m=-1e30f;
    for(int dy=-1;dy<=1;dy++){ int iy=y+dy; if(iy<0||iy>=28) continue;
      for(int dx=-1;dx<=1;dx++){ int ix=x+dx; if(ix<0||ix>=28) continue;
        m=fmaxf(m,xs[iy*28+ix]); } }
    mp[i]=m;
  }
  __syncthreads();
  if(tid<100){
    int ii=tid/10, j=tid%10;
    const float fw[4]={0.125f,0.375f,0.375f,0.125f};
    float s=0;
    for(int ky=0;ky<4;ky++){ int rr=refl(3*ii+ky);
      for(int kx=0;kx<4;kx++){ int cc=refl(3*j+kx);
        s += fw[ky]*fw[kx]*mp[rr*28+cc]; } }
    xt[tid]=s;
  }
  __syncthreads();
  if(tid<100){
    int r=tid/10, j=tid%10;
    float s=0;
    for(int kh=0;kh<11;kh++){ int a=r+kh-5; if(a<0||a>=10) continue;
      for(int kw=0;kw<3;kw++){ int b2=j+kw-1; if(b2<0||b2>=10) continue;
        s+=xt[a*10+b2]*h1w[(size_t)c*33+kh*3+kw]; } }
    for(int kh=0;kh<3;kh++){ int a=r+kh-1; if(a<0||a>=10) continue;
      for(int kw=0;kw<11;kw++){ int b2=j+kw-5; if(b2<0||b2>=10) continue;
        s+=xt[a*10+b2]*v1w[(size_t)c*33+kh*11+kw]; } }
    { int t=20*r+j; int r2=t/19, j2=t%19;
      for(int kh=0;kh<11;kh++){ int a=r2+kh-5; if(a<0||a>=10) continue;
        for(int kw=0;kw<3;kw++){ int b2=j2+kw-1; if(b2<0||b2>=19) continue;
          int i2=19*a+b2; int row=i2/20, col=i2%20;
          if(col<10) s+=xt[row*10+col]*h2w[(size_t)c*33+kh*3+kw]; } } }
    { int t=20*j+r; int p=t%19, q=t/19;
      for(int kh=0;kh<3;kh++){ int a=p+kh-1; if(a<0||a>=19) continue;
        for(int kw=0;kw<11;kw++){ int b2=q+kw-5; if(b2<0||b2>=10) continue;
          int i2=19*b2+a; int row=i2/20, col=i2%20;
          if(col<10) s+=xt[col*10+row]*v2w[(size_t)c*33+kh*11+kw]; } } }
    s = bnorm(s,bnp,c,C);
    attv[tid] = 1.f/(1.f+__expf(-s));
  }
  __syncthreads();
  float* dst = xa + ((size_t)(b*DIM+64+c))*LPIX;
  for(int i=tid;i<LPIX;i+=256){
    int y=i/28, x=i%28;
    float a = attv[((y*10)/28)*10 + (x*10)/28];
    dst[i] = xs[i]*a;
  }
}

// qkv: 12 groups x 16 output channels, 2 pixels per thread (8 loads in flight / chunk)
DEV void body_qkv(int blk, int tid, const float* X, const float* w, float* qkvb){
  int og = blk % 12;
  int p0 = (blk/12)*512 + tid;
  if(p0 >= NPIX) return;
  int o0 = og*16;
  int b0 = p0/LPIX, l0 = p0%LPIX;
  int p1 = p0 + 256;
  bool has1 = p1 < NPIX;
  int b1 = has1 ? p1/LPIX : b0, l1 = has1 ? p1%LPIX : l0;
  const float* xp0 = X + ((size_t)(b0*DIM+192))*LPIX + l0;
  const float* xp1 = X + ((size_t)(b1*DIM+192))*LPIX + l1;
  float s0[16], s1[16];
  #pragma unroll
  for(int t=0;t<16;t++){ s0[t]=0.f; s1[t]=0.f; }
  for(int c=0;c<C;c+=4){
    float a0=xp0[(size_t)c*LPIX],     a1=xp0[(size_t)(c+1)*LPIX],
          a2=xp0[(size_t)(c+2)*LPIX], a3=xp0[(size_t)(c+3)*LPIX];
    float e0=xp1[(size_t)c*LPIX],     e1=xp1[(size_t)(c+1)*LPIX],
          e2=xp1[(size_t)(c+2)*LPIX], e3=xp1[(size_t)(c+3)*LPIX];
    #pragma unroll
    for(int t=0;t<16;t++){
      const float* wr = w + (size_t)(o0+t)*C + c;
      float w0=wr[0], w1=wr[1], w2=wr[2], w3=wr[3];
      s0[t] += w0*a0 + w1*a1 + w2*a2 + w3*a3;
      s1[t] += w0*e0 + w1*e1 + w2*e2 + w3*e3;
    }
  }
  int which=o0>>6, head0=(o0&63)>>2;
  #pragma unroll
  for(int t4=0;t4<4;t4++){
    float4* dst = (float4*)(qkvb + (size_t)which*B*NH*LPIX*HD + ((size_t)((b0*NH+head0+t4)*LPIX+l0))*HD);
    *dst = make_float4(s0[4*t4],s0[4*t4+1],s0[4*t4+2],s0[4*t4+3]);
  }
  if(has1){
    #pragma unroll
    for(int t4=0;t4<4;t4++){
      float4* dst = (float4*)(qkvb + (size_t)which*B*NH*LPIX*HD + ((size_t)((b1*NH+head0+t4)*LPIX+l1))*HD);
      *dst = make_float4(s1[4*t4],s1[4*t4+1],s1[4*t4+2],s1[4*t4+3]);
    }
  }
}

// bcdtssd: single 4x784 LDS buffer.
// og<32: conv -> bc2 only.  og>=32: conv into 13 regs -> write back in place ->
// parallel per-wave softmax (plane wv per wave) -> wgt. 3 barriers, no serialization.
DEV void body_bcdtssd(int blk, int tid, float* smem, const float* X, const float* w, const float* dww,
                      float* bc2, float* wgt){
  int b = blk/48, og = blk%48; int o0=og*4;
  float* bc1s = smem;            // 4*784
  const float* xp = X + ((size_t)(b*DIM+128))*LPIX;
  // stage-1: pixels {tid, tid+256, tid+512} fused in one c-loop (12 loads in flight),
  // 16-pixel tail (768..783) by threads 0..15.
  {
    int l0=tid, l1=tid+256, l2=tid+512;
    float acc0[4]={0,0,0,0}, acc1[4]={0,0,0,0}, acc2[4]={0,0,0,0};
    for(int c=0;c<C;c+=4){
      float x00=xp[(size_t)c*LPIX+l0],     x01=xp[(size_t)(c+1)*LPIX+l0],
            x02=xp[(size_t)(c+2)*LPIX+l0], x03=xp[(size_t)(c+3)*LPIX+l0];
      float x10=xp[(size_t)c*LPIX+l1],     x11=xp[(size_t)(c+1)*LPIX+l1],
            x12=xp[(size_t)(c+2)*LPIX+l1], x13=xp[(size_t)(c+3)*LPIX+l1];
      float x20=xp[(size_t)c*LPIX+l2],     x21=xp[(size_t)(c+1)*LPIX+l2],
            x22=xp[(size_t)(c+2)*LPIX+l2], x23=xp[(size_t)(c+3)*LPIX+l2];
      #pragma unroll
      for(int t=0;t<4;t++){
        const float* wr = w + (size_t)(o0+t)*C + c;
        float w0=wr[0], w1=wr[1], w2=wr[2], w3=wr[3];
        acc0[t] += w0*x00 + w1*x01 + w2*x02 + w3*x03;
        acc1[t] += w0*x10 + w1*x11 + w2*x12 + w3*x13;
        acc2[t] += w0*x20 + w1*x21 + w2*x22 + w3*x23;
      }
    }
    #pragma unroll
    for(int t=0;t<4;t++){
      bc1s[t*LPIX+l0]=acc0[t];
      bc1s[t*LPIX+l1]=acc1[t];
      bc1s[t*LPIX+l2]=acc2[t];
    }
    if(tid<16){
      int l=768+tid;
      float a0=0,a1=0,a2=0,a3=0;
      for(int c=0;c<C;c+=4){
        float x0=xp[(size_t)c*LPIX+l],     x1=xp[(size_t)(c+1)*LPIX+l],
              x2=xp[(size_t)(c+2)*LPIX+l], x3=xp[(size_t)(c+3)*LPIX+l];
        const float* w0p = w + (size_t)(o0+0)*C + c;
        const float* w1p = w + (size_t)(o0+1)*C + c;
        const float* w2p = w + (size_t)(o0+2)*C + c;
        const float* w3p = w + (size_t)(o0+3)*C + c;
        a0 += w0p[0]*x0 + w0p[1]*x1 + w0p[2]*x2 + w0p[3]*x3;
        a1 += w1p[0]*x0 + w1p[1]*x1 + w1p[2]*x2 + w1p[3]*x3;
        a2 += w2p[0]*x0 + w2p[1]*x1 + w2p[2]*x2 + w2p[3]*x3;
        a3 += w3p[0]*x0 + w3p[1]*x1 + w3p[2]*x2 + w3p[3]*x3;
      }
      bc1s[0*LPIX+l]=a0; bc1s[1*LPIX+l]=a1; bc1s[2*LPIX+l]=a2; bc1s[3*LPIX+l]=a3;
    }
  }
  __syncthreads();
  if(og < 32){
    // B/C planes: 3x3 depthwise conv, write bc2 only
    for(int i=tid;i<4*LPIX;i+=256){
      int oo=i/LPIX, l=i%LPIX; int y=l/28, x=l%28;
      const float* p = bc1s + oo*LPIX;
      const float* wk = dww + (size_t)(o0+oo)*9;
      float s=0;
      for(int ky=0;ky<3;ky++){ int iy=y+ky-1; if(iy<0||iy>=28) continue;
        for(int kx=0;kx<3;kx++){ int ix=x+kx-1; if(ix<0||ix>=28) continue;
          s += p[iy*28+ix]*wk[ky*3+kx]; } }
      bc2[((size_t)(b*192+o0+oo))*LPIX + l] = s;
    }
  } else {
    // conv into registers (13 per thread), write back in place, parallel softmax
    float cv[13];
    #pragma unroll
    for(int k=0;k<13;k++){
      int i = tid + k*256;
      if(i < 4*LPIX){
        int oo=i/LPIX, l=i%LPIX; int y=l/28, x=l%28;
        const float* p = bc1s + oo*LPIX;
        const float* wk = dww + (size_t)(o0+oo)*9;
        float s=0;
        for(int ky=0;ky<3;ky++){ int iy=y+ky-1; if(iy<0||iy>=28) continue;
          for(int kx=0;kx<3;kx++){ int ix=x+kx-1; if(ix<0||ix>=28) continue;
            s += p[iy*28+ix]*wk[ky*3+kx]; } }
        cv[k]=s;
      }
    }
    __syncthreads();
    #pragma unroll
    for(int k=0;k<13;k++){ int i=tid+k*256; if(i<4*LPIX) bc1s[i]=cv[k]; }
    __syncthreads();
    int wv = tid>>6, lane = tid&63;
    float* row = bc1s + wv*LPIX;
    float mx = -1e30f;
    for(int l=lane;l<LPIX;l+=64) mx = fmaxf(mx, row[l]);
    for(int off=32;off;off>>=1) mx = fmaxf(mx, __shfl_xor(mx,off));
    float sum=0;
    for(int l=lane;l<LPIX;l+=64){ float e=__expf(row[l]-mx); row[l]=e; sum+=e; }
    for(int off=32;off;off>>=1) sum += __shfl_xor(sum,off);
    float inv = 1.f/sum;
    int s_ = o0-128+wv;
    float* wp = wgt + ((size_t)(b*S+s_))*LPIX;
    for(int l=lane;l<LPIX;l+=64) wp[l] = row[l]*inv;
  }
}

// attn: 1024 blocks = (bh, ms-slice, row-half). SoA K/V in LDS; even/odd key pairs
// written as adjacent scalar FMA chains so SLP forms v_pk_fma_f32.
DEV void body_attn(int blk, int tid, float* smem, const float* qkvb,
                   float* ob, float* lsb){
  int bh = blk >> 3, ms = (blk >> 1) & 3, half = blk & 1;
  int b = bh>>4, h = bh&15;
  float* kx = smem;        float* ky = smem+196;
  float* kz = smem+392;    float* kw = smem+588;
  float* vx = smem+784;    float* vy = smem+980;
  float* vz = smem+1176;   float* vw = smem+1372;
  const float4* k4 = (const float4*)(qkvb + (size_t)(B*NH + bh)*LPIX*HD) + ms*196;
  const float4* v4 = (const float4*)(qkvb + (size_t)(2*B*NH + bh)*LPIX*HD) + ms*196;
  for(int i=tid;i<196;i+=256){
    float4 kv=k4[i]; kx[i]=kv.x; ky[i]=kv.y; kz[i]=kv.z; kw[i]=kv.w;
    float4 vv=v4[i]; vx[i]=vv.x; vy[i]=vv.y; vz[i]=vv.z; vw[i]=vv.w;
  }
  const float SC = 0.5f*1.44269504f;
  const float4* q4 = (const float4*)(qkvb + (size_t)bh*LPIX*HD);
  int rbase = half*392;
  int r0 = rbase + tid;
  int r1 = rbase + 256 + tid;
  bool has1 = tid < 136;
  float4 qa = q4[r0];
  float4 qb = has1 ? q4[r1] : qa;
  qa.x*=SC; qa.y*=SC; qa.z*=SC; qa.w*=SC;
  qb.x*=SC; qb.y*=SC; qb.z*=SC; qb.w*=SC;
  __syncthreads();
  float* obp = ob + (size_t)ms*B*LPIX*C;
  float* lsq = lsb + (size_t)ms*B*NH*LPIX + (size_t)bh*LPIX;
  // per-row accumulators: even/odd key lanes kept separate (packed pairs)
  float l0x=0,l0y=0, a0xx=0,a0xy=0, a0yx=0,a0yy=0, a0zx=0,a0zy=0, a0wx=0,a0wy=0;
  float l1x=0,l1y=0, a1xx=0,a1xy=0, a1yx=0,a1yy=0, a1zx=0,a1zy=0, a1wx=0,a1wy=0;
  for(int m=0;m<98;m++){
    float2 kX=*(const float2*)(kx+2*m), kY=*(const float2*)(ky+2*m),
           kZ=*(const float2*)(kz+2*m), kW=*(const float2*)(kw+2*m);
    float2 vX=*(const float2*)(vx+2*m), vY=*(const float2*)(vy+2*m),
           vZ=*(const float2*)(vz+2*m), vW=*(const float2*)(vw+2*m);
    // row 0
    float s0x = qa.x*kX.x + qa.y*kY.x + qa.z*kZ.x + qa.w*kW.x;
    float s0y = qa.x*kX.y + qa.y*kY.y + qa.z*kZ.y + qa.w*kW.y;
    float p0x = __builtin_amdgcn_exp2f(s0x);
    float p0y = __builtin_amdgcn_exp2f(s0y);
    l0x += p0x;        l0y += p0y;
    a0xx += p0x*vX.x;  a0xy += p0y*vX.y;
    a0yx += p0x*vY.x;  a0yy += p0y*vY.y;
    a0zx += p0x*vZ.x;  a0zy += p0y*vZ.y;
    a0wx += p0x*vW.x;  a0wy += p0y*vW.y;
    // row 1
    float s1x = qb.x*kX.x + qb.y*kY.x + qb.z*kZ.x + qb.w*kW.x;
    float s1y = qb.x*kX.y + qb.y*kY.y + qb.z*kZ.y + qb.w*kW.y;
    float p1x = __builtin_amdgcn_exp2f(s1x);
    float p1y = __builtin_amdgcn_exp2f(s1y);
    l1x += p1x;        l1y += p1y;
    a1xx += p1x*vX.x;  a1xy += p1y*vX.y;
    a1yx += p1x*vY.x;  a1yy += p1y*vY.y;
    a1zx += p1x*vZ.x;  a1zy += p1y*vZ.y;
    a1wx += p1x*vW.x;  a1wy += p1y*vW.y;
  }
  *(float4*)(obp + ((size_t)(b*LPIX+r0))*C + h*4) =
      make_float4(a0xx+a0xy, a0yx+a0yy, a0zx+a0zy, a0wx+a0wy);
  lsq[r0] = l0x+l0y;
  if(has1){
    *(float4*)(obp + ((size_t)(b*LPIX+r1))*C + h*4) =
        make_float4(a1xx+a1xy, a1yx+a1yy, a1zx+a1zy, a1wx+a1wy);
    lsq[r1] = l1x+l1y;
  }
}

DEV void body_star(int blk, int tid, const float* x1o, const float* f1w,const float* f1b,const float* f2w,const float* f2b,float* t1){
  int jg, b, l; if(!upix(blk, tid, 32, jg, b, l)) return;
  int j0=jg*4;
  const float* xp = x1o + (size_t)b*C*LPIX + l;
  float a[4], g[4];
  for(int t=0;t<4;t++){ a[t]=f1b[j0+t]; g[t]=f2b[j0+t]; }
  for(int c=0;c<C;c++){
    float xv = xp[(size_t)c*LPIX];
    for(int t=0;t<4;t++){ a[t]+=f1w[(size_t)(j0+t)*C+c]*xv; g[t]+=f2w[(size_t)(j0+t)*C+c]*xv; }
  }
  for(int t=0;t<4;t++){
    float av = fminf(fmaxf(a[t],0.f),6.f);
    t1[((size_t)(b*HID+j0+t))*LPIX + l] = av*g[t];
  }
}

// gproj: ngroups=4, 16 output channels per thread.
DEV void body_gproj(int blk, int tid, const float* t1, const float* gw,const float* gb,const float* bnp,float* t2){
  int cg, b, l; if(!upix(blk, tid, 4, cg, b, l)) return;
  int c0=cg*16;
  const float* tp = t1 + (size_t)b*HID*LPIX + l;
  float s[16];
  #pragma unroll
  for(int t=0;t<16;t++) s[t]=gb[c0+t];
  for(int j=0;j<HID;j++){
    float xv = tp[(size_t)j*LPIX];
    #pragma unroll
    for(int t=0;t<16;t++) s[t]+=gw[(size_t)(c0+t)*HID+j]*xv;
  }
  #pragma unroll
  for(int t=0;t<16;t++) t2[((size_t)(b*C+c0+t))*LPIX + l]=bnorm(s[t],bnp,c0+t,C);
}

// x4: ngroups=4, 16 output channels per thread; ob partials read as float4.
DEV void body_x4(int blk, int tid, const float* X, const float* ob, const float* lsb,
                 const float* projw, const float* bnp, float* xa){
  int cg, b, l; if(!upix(blk, tid, 4, cg, b, l)) return;
  int c0=cg*16;
  const float* p0 = ob + ((size_t)(b*LPIX+l))*C;
  const float* p1 = p0 + (size_t)B*LPIX*C;
  const float* p2 = p1 + (size_t)B*LPIX*C;
  const float* p3 = p2 + (size_t)B*LPIX*C;
  float s[16];
  #pragma unroll
  for(int t=0;t<16;t++) s[t]=0.f;
  for(int h=0;h<NH;h++){
    size_t li = ((size_t)(b*NH+h))*LPIX + l;
    float lsum = lsb[li] + lsb[(size_t)B*NH*LPIX+li] + lsb[(size_t)2*B*NH*LPIX+li] + lsb[(size_t)3*B*NH*LPIX+li];
    float iv = 1.f/lsum;
    float4 q0=*(const float4*)(p0+h*4), q1=*(const float4*)(p1+h*4),
           q2=*(const float4*)(p2+h*4), q3=*(const float4*)(p3+h*4);
    float ov0=(q0.x+q1.x+q2.x+q3.x)*iv;
    float ov1=(q0.y+q1.y+q2.y+q3.y)*iv;
    float ov2=(q0.z+q1.z+q2.z+q3.z)*iv;
    float ov3=(q0.w+q1.w+q2.w+q3.w)*iv;
    const float* pw = projw + h*4;
    #pragma unroll
    for(int t=0;t<16;t++){
      const float* pr = pw + (size_t)(c0+t)*C;
      s[t] += pr[0]*ov0 + pr[1]*ov1 + pr[2]*ov2 + pr[3]*ov3;
    }
  }
  #pragma unroll
  for(int t=0;t<16;t++){
    float v = s[t] + X[((size_t)(b*DIM+192+c0+t))*LPIX + l];
    xa[((size_t)(b*DIM+192+c0+t))*LPIX + l] = bnorm(v,bnp,c0+t,C);
  }
}

// h: l-tile split into 2x98 halves -> LDS 2*16*99 floats (12.7KB)
DEV void body_h(int blk, int tid, float* smem, const float* X, const float* wgt, const float* bc2, float* hq){
  int b = blk >> 6, sub = blk & 63;
  int tile = sub >> 2, qq = sub & 3;
  int ct = (tile>>2)*16, st = (tile&3)*16;
  float (*Xs)[99] = (float(*)[99])smem;
  float (*Ws)[99] = (float(*)[99])(smem + 16*99);
  int tc = tid>>4, ts = tid&15;
  float acc=0;
  #pragma unroll
  for(int half=0;half<2;half++){
    int lb = qq*196 + half*98;
    for(int i=tid;i<16*98;i+=256){
      int r=i/98, col=i%98;
      Xs[r][col] = X[((size_t)(b*DIM+128+ct+r))*LPIX + lb + col];
      Ws[r][col] = wgt[((size_t)(b*S+st+r))*LPIX + lb + col]
                 * bc2[((size_t)(b*192+st+r))*LPIX + lb + col];
    }
    __syncthreads();
    #pragma unroll 7
    for(int l=0;l<98;l++) acc += Xs[tc][l]*Ws[ts][l];
    __syncthreads();
  }
  hq[(size_t)qq*B*C*S + ((size_t)(b*C+ct+tc))*S + st+ts] = acc;
}

// dw2t: zero-padded 34x34 LDS tile, straight-line 7x7 conv
DEV void body_dw2t(int bc, int tid, float* xs, const float* t2, const float* w, const float* bias, float* xa){
  int c = bc & 63, b = bc >> 6;
  const float* tp = t2 + ((size_t)(b*C+c))*LPIX;
  for(int i=tid;i<34*34;i+=256) xs[i]=0.f;
  __syncthreads();
  for(int i=tid;i<LPIX;i+=256){ int y=i/28, x=i%28; xs[(y+3)*34+(x+3)]=tp[i]; }
  __syncthreads();
  const float* wc = w + (size_t)c*49;
  float bs = bias[c];
  for(int i=tid;i<LPIX;i+=256){
    int y=i/28, x=i%28;
    float s = bs;
    #pragma unroll
    for(int ky=0;ky<7;ky++){
      #pragma unroll
      for(int kx=0;kx<7;kx++)
        s += xs[(y+ky)*34 + x+kx]*wc[ky*7+kx];
    }
    xa[((size_t)(b*DIM+c))*LPIX + i] = s;
  }
}

DEV void body_mixho(int blk, int tid, float* smem, const float* hq, const float* hzw,
                    const float* Dp, const float* outw, float* ho){
  int b = blk >> 3, st = (blk & 7) * 8;
  float (*hs2)[8] = (float(*)[8])smem;
  float (*g1s)[8] = (float(*)[8])(smem + C*8);
  for(int i=tid;i<C*8;i+=256){
    int k=i>>3, si=i&7;
    size_t off = ((size_t)(b*C+k))*S + st + si;
    hs2[k][si] = hq[off] + hq[(size_t)B*C*S+off] + hq[(size_t)2*B*C*S+off] + hq[(size_t)3*B*C*S+off];
  }
  __syncthreads();
  float D = Dp[0];
  for(int i=tid;i<C*8;i+=256){
    int c=i>>3, si=i&7;
    float hv=0, zv=0;
    for(int k=0;k<C;k++){ float x=hs2[k][si]; hv+=hzw[(size_t)c*C+k]*x; zv+=hzw[(size_t)(C+c)*C+k]*x; }
    float sil = zv/(1.f+__expf(-zv));
    g1s[c][si]=hv*sil+hv*D;
  }
  __syncthreads();
  for(int i=tid;i<C*8;i+=256){
    int c=i>>3, si=i&7;
    float acc=0;
    for(int k=0;k<C;k++) acc+=outw[(size_t)c*C+k]*g1s[k][si];
    ho[((size_t)(b*C+c))*S + st + si]=acc;
  }
}

DEV void body_x3(int blk, int tid, const float* ho, const float* bc2, float* xa){
  int cg, b, l; if(!upix(blk, tid, 16, cg, b, l)) return;
  int c0=cg*4;
  const float* hp = ho + (size_t)(b*C+c0)*S;
  const float* cm = bc2 + ((size_t)(b*192+64))*LPIX + l;
  float s[4]={0,0,0,0};
  for(int s_=0;s_<S;s_++){
    float cv = cm[(size_t)s_*LPIX];
    for(int t=0;t<4;t++) s[t] += hp[(size_t)t*S+s_]*cv;
  }
  for(int t=0;t<4;t++)
    xa[((size_t)(b*DIM+128+c0+t))*LPIX + l] = s[t];
}

// ================= stage kernels =================
// S1: [0,384)=bcdtssd+softmax  [384,896)=branch2  [896,896+QB)=qkv  [..,..+512)=dw1t
// LDS 4*784 floats = 12.5KB; no launch_bounds (r5 lesson)
__global__ void k_s1(const float* X,
                     const float* bcdt_w, const float* ssd_dw, float* bc2, float* wgt,
                     const float* h1w,const float* v1w,const float* h2w,const float* v2w,const float* bn_mra,
                     const float* qkv_w, float* qkvb,
                     const float* dw1_w,const float* dw1_b,const float* bn_dw1,
                     float* xa, float* x1o){
  __shared__ float smem[4*LPIX];
  int blk = blockIdx.x, tid = threadIdx.x;
  if(blk < 384)            body_bcdtssd(blk, tid, smem, X, bcdt_w, ssd_dw, bc2, wgt);
  else if(blk < 896)       body_branch2(blk-384, tid, smem, X, h1w,v1w,h2w,v2w, bn_mra, xa);
  else if(blk < 896+QB)    body_qkv(blk-896, tid, X, qkv_w, qkvb);
  else                     body_dw1t(blk-(896+QB), tid, smem, X, dw1_w, dw1_b, bn_dw1, x1o);
}

// S2: [0,1024)=attn  [1024,1024+32*CH)=star  [..,..+512)=h
// LDS 3168 floats = 12.7KB
__global__ void k_s2(const float* qkvb, float* ob, float* lsb,
                     const float* x1o, const float* f1w,const float* f1b,const float* f2w,const float* f2b, float* t1,
                     const float* X, const float* wgt, const float* bc2, float* hq){
  __shared__ float smem[3168];
  int blk = blockIdx.x, tid = threadIdx.x;
  if(blk < 1024)            body_attn(blk, tid, smem, qkvb, ob, lsb);
  else if(blk < 1024+32*CH) body_star(blk-1024, tid, x1o, f1w,f1b,f2w,f2b, t1);
  else                      body_h(blk-(1024+32*CH), tid, smem, X, wgt, bc2, hq);
}

// S3: [0,64)=mixho  [64,64+4*CH)=gproj  [64+4*CH,64+8*CH)=x4
__global__ void k_s3(const float* t1, const float* gw,const float* gb,const float* bn_g, float* t2,
                     const float* X, const float* ob, const float* lsb,
                     const float* projw, const float* bn_n4, float* xa,
                     const float* hq, const float* hzw, const float* Dp, const float* outw, float* ho){
  __shared__ float smem[2*C*8];
  int blk = blockIdx.x, tid = threadIdx.x;
  if(blk < 64)           body_mixho(blk, tid, smem, hq, hzw, Dp, outw, ho);
  else if(blk < 64+4*CH) body_gproj(blk-64, tid, t1, gw, gb, bn_g, t2);
  else                   body_x4(blk-(64+4*CH), tid, X, ob, lsb, projw, bn_n4, xa);
}

// S4: [0,512)=dw2t  [512,512+16*CH)=x3
__global__ void k_s4(const float* t2, const float* dw2_w, const float* dw2_b, float* xa,
                     const float* ho, const float* bc2){
  __shared__ float smem[34*34];
  int blk = blockIdx.x, tid = threadIdx.x;
  if(blk < 512) body_dw2t(blk, tid, smem, t2, dw2_w, dw2_b, xa);
  else          body_x3(blk-512, tid, ho, bc2, xa);
}

// mid: 32 groups x 4 outputs (800 blocks)
__global__ void k_mid(const float* xa, const float* m1w, const float* bnp, float* mid){
  int jg, b, l; if(!upix(blockIdx.x, threadIdx.x, 32, jg, b, l)) return;
  int j0=jg*4;
  const float* xp = xa + (size_t)b*DIM*LPIX + l;
  float s[4]={0,0,0,0};
  for(int c=0;c<DIM;c++){
    float xv=xp[(size_t)c*LPIX];
    for(int t=0;t<4;t++) s[t]+=m1w[(size_t)(j0+t)*DIM+c]*xv;
  }
  for(int t=0;t<4;t++)
    mid[((size_t)(b*HID+j0+t))*LPIX + l] = fmaxf(bnorm(s[t],bnp,j0+t,HID),0.f);
}

// out: 32 groups x 8 outputs (800 blocks)
__global__ void k_out(const float* X, const float* mid, const float* m2w, const float* bnp, float* out){
  int cg, b, l; if(!upix(blockIdx.x, threadIdx.x, 32, cg, b, l)) return;
  int c0=cg*8;
  const float* mp_ = mid + (size_t)b*HID*LPIX + l;
  float s[8]={0,0,0,0,0,0,0,0};
  for(int j=0;j<HID;j++){
    float mv=mp_[(size_t)j*LPIX];
    for(int t=0;t<8;t++) s[t]+=m2w[(size_t)(c0+t)*HID+j]*mv;
  }
  for(int t=0;t<8;t++){
    size_t oi = ((size_t)(b*DIM+c0+t))*LPIX + l;
    out[oi] = bnorm(s[t],bnp,c0+t,DIM) + X[oi];
  }
}

extern "C" void kernel_launch(void* const* d_in, const int* in_sizes, int n_in,
                              void* d_out, int out_size, void* d_ws, size_t ws_size,
                              hipStream_t stream) {
  const float* X      = (const float*)d_in[0];
  const float* dw1_w  = (const float*)d_in[1];
  const float* dw1_b  = (const float*)d_in[2];
  const float* bn_dw1 = (const float*)d_in[3];
  const float* f1_w   = (const float*)d_in[4];
  const float* f1_b   = (const float*)d_in[5];
  const float* f2_w   = (const float*)d_in[6];
  const float* f2_b   = (const float*)d_in[7];
  const float* g_w    = (const float*)d_in[8];
  const float* g_b    = (const float*)d_in[9];
  const float* bn_g   = (const float*)d_in[10];
  const float* dw2_w  = (const float*)d_in[11];
  const float* dw2_b  = (const float*)d_in[12];
  const float* hatt1w = (const float*)d_in[13];
  const float* vatt1w = (const float*)d_in[14];
  const float* hatt2w = (const float*)d_in[15];
  const float* vatt2w = (const float*)d_in[16];
  const float* bn_mra = (const float*)d_in[17];
  const float* bcdt_w = (const float*)d_in[18];
  const float* ssd_dw = (const float*)d_in[19];
  const float* hz_w   = (const float*)d_in[20];
  const float* out_w  = (const float*)d_in[21];
  const float* D_p    = (const float*)d_in[23];
  const float* qkv_w  = (const float*)d_in[24];
  const float* proj_w = (const float*)d_in[25];
  const float* bn_n4  = (const float*)d_in[26];
  const float* mlp1_w = (const float*)d_in[27];
  const float* bn_mlp = (const float*)d_in[28];
  const float* mlp2_w = (const float*)d_in[29];
  const float* bn_n1  = (const float*)d_in[30];

  float* ws   = (float*)d_ws;
  float* x1o  = ws+OFF_X1O;  float* t1  = ws+OFF_T1;  float* t2  = ws+OFF_T2;
  float* xa   = ws+OFF_XA;   float* bc2 = ws+OFF_BC2; float* wgt = ws+OFF_WGT;
  float* hq   = ws+OFF_H;    float* ho  = ws+OFF_HO;  float* qkvb= ws+OFF_QKV;
  float* ob   = ws+OFF_O;    float* lsb = ws+OFF_LS;  float* mid = ws+OFF_MID;

  dim3 blk(256);

  k_s1 <<<dim3(896+QB+512),blk,0,stream>>>(X, bcdt_w, ssd_dw, bc2, wgt,
                                     hatt1w,vatt1w,hatt2w,vatt2w,bn_mra,
                                     qkv_w, qkvb, dw1_w,dw1_b,bn_dw1, xa, x1o);
  k_s2 <<<dim3(1024+32*CH+512),blk,0,stream>>>(qkvb, ob, lsb,
                                     x1o, f1_w,f1_b,f2_w,f2_b, t1,
                                     X, wgt, bc2, hq);
  k_s3 <<<dim3(64+8*CH),blk,0,stream>>>(t1, g_w,g_b,bn_g, t2,
                                     X, ob, lsb, proj_w, bn_n4, xa,
                                     hq, hz_w, D_p, out_w, ho);
  k_s4 <<<dim3(512+16*CH),blk,0,stream>>>(t2, dw2_w, dw2_b, xa, ho, bc2);
  k_mid<<<dim3(32*CH),blk,0,stream>>>(xa,mlp1_w,bn_mlp,mid);
  k_out<<<dim3(32*CH),blk,0,stream>>>(X,mid,mlp2_w,bn_n1,(float*)d_out);
}

// Round 8
// 276.557 us; speedup vs baseline: 1.0551x; 1.0551x over previous
//
#include <hip/hip_runtime.h>
#include <hip/hip_bf16.h>
#include <math.h>

#define DEV __device__ __forceinline__

constexpr int B=8, C=64, DIM=256, HID=128, S=64, NH=16, HD=4, LPIX=784;
constexpr int NPIX = B*LPIX;          // 6272
constexpr int CH   = (NPIX+255)/256;  // 25
constexpr int QB   = 12*((NPIX+511)/512); // 156 qkv blocks (12 groups x 13 chunks)

constexpr size_t OFF_X1O = 0;
constexpr size_t OFF_T1  = OFF_X1O + (size_t)B*C*LPIX;
constexpr size_t OFF_T2  = OFF_T1  + (size_t)B*HID*LPIX;
constexpr size_t OFF_XA  = OFF_T2  + (size_t)B*C*LPIX;
constexpr size_t OFF_BC2 = OFF_XA  + (size_t)B*DIM*LPIX;
constexpr size_t OFF_WGT = OFF_BC2 + (size_t)B*192*LPIX;        // B*S*L (pure softmax probs)
constexpr size_t OFF_H   = OFF_WGT + (size_t)B*S*LPIX;          // 4 * B*C*S
constexpr size_t OFF_HO  = OFF_H   + (size_t)4*B*C*S;
constexpr size_t OFF_QKV = OFF_HO  + (size_t)B*C*S;
constexpr size_t OFF_O   = OFF_QKV + (size_t)3*B*NH*LPIX*HD;    // 4 * B*L*C partials
constexpr size_t OFF_LS  = OFF_O   + (size_t)4*B*LPIX*C;        // 4 * B*NH*L
constexpr size_t OFF_MID = OFF_LS  + (size_t)4*B*NH*LPIX;

DEV float bnorm(float x, const float* p, int c, int nc){
  float g=p[c], bb=p[nc+c], m=p[2*nc+c], v=p[3*nc+c];
  return (x-m)*(g*rsqrtf(v+1e-5f))+bb;
}
DEV int refl(int p){ int k=p-1; if(k<0)k=-k; if(k>27)k=54-k; return k; }

DEV bool upix(int blk, int tid, int ngroups, int& grp, int& b, int& l){
  grp = blk % ngroups;
  int gidx = (blk/ngroups)*256 + tid;
  if(gidx >= NPIX) return false;
  b = gidx / LPIX; l = gidx % LPIX;
  return true;
}

// ================= bodies =================
// dw1t: zero-padded 34x34 LDS tile -> straight-line 7x7 conv (no bounds branches)
DEV void body_dw1t(int bc, int tid, float* xs, const float* X, const float* w, const float* bias, const float* bnp, float* out){
  int c = bc & 63, b = bc >> 6;
  const float* xp = X + ((size_t)(b*DIM+c))*LPIX;
  for(int i=tid;i<34*34;i+=256) xs[i]=0.f;
  __syncthreads();
  for(int i=tid;i<LPIX;i+=256){ int y=i/28, x=i%28; xs[(y+3)*34+(x+3)]=xp[i]; }
  __syncthreads();
  const float* wc = w + (size_t)c*49;
  float bs = bias[c];
  for(int i=tid;i<LPIX;i+=256){
    int y=i/28, x=i%28;
    float s = bs;
    #pragma unroll
    for(int ky=0;ky<7;ky++){
      #pragma unroll
      for(int kx=0;kx<7;kx++)
        s += xs[(y+ky)*34 + x+kx]*wc[ky*7+kx];
    }
    out[((size_t)(b*C+c))*LPIX + i] = bnorm(s,bnp,c,C);
  }
}

DEV void body_branch2(int bc, int tid, float* smem, const float* X,
                      const float* h1w,const float* v1w,const float* h2w,const float* v2w,
                      const float* bnp, float* xa){
  int c = bc & 63, b = bc >> 6;
  float* xs  = smem;
  float* mp  = smem+LPIX;
  float* xt  = smem+2*LPIX;
  float* attv= smem+2*LPIX+100;
  const float* xp = X + ((size_t)(b*DIM+64+c))*LPIX;
  for(int i=tid;i<LPIX;i+=256) xs[i]=xp[i];
  __syncthreads();
  for(int i=tid;i<LPIX;i+=256){
    int y=i/28, x=i%28;
    float m=-1e30f;
    for(int dy=-1;dy<=1;dy++){ int iy=y+dy; if(iy<0||iy>=28) continue;
      for(int dx=-1;dx<=1;dx++){ int ix=x+dx; if(ix<0||ix>=28) continue;
        m=fmaxf(m,xs[iy*28+ix]); } }
    mp[i]=m;
  }
  __syncthreads();
  if(tid<100){
    int ii=tid/10, j=tid%10;
    const float fw[4]={0.125f,0.375f,0.375f,0.125f};
    float s=0;
    for(int ky=0;ky<4;ky++){ int rr=refl(3*ii+ky);
      for(int kx=0;kx<4;kx++){ int cc=refl(3*j+kx);
        s += fw[ky]*fw[kx]*mp[rr*28+cc]; } }
    xt[tid]=s;
  }
  __syncthreads();
  if(tid<100){
    int r=tid/10, j=tid%10;
    float s=0;
    for(int kh=0;kh<11;kh++){ int a=r+kh-5; if(a<0||a>=10) continue;
      for(int kw=0;kw<3;kw++){ int b2=j+kw-1; if(b2<0||b2>=10) continue;
        s+=xt[a*10+b2]*h1w[(size_t)c*33+kh*3+kw]; } }
    for(int kh=0;kh<3;kh++){ int a=r+kh-1; if(a<0||a>=10) continue;
      for(int kw=0;kw<11;kw++){ int b2=j+kw-5; if(b2<0||b2>=10) continue;
        s+=xt[a*10+b2]*v1w[(size_t)c*33+kh*11+kw]; } }
    { int t=20*r+j; int r2=t/19, j2=t%19;
      for(int kh=0;kh<11;kh++){ int a=r2+kh-5; if(a<0||a>=10) continue;
        for(int kw=0;kw<3;kw++){ int b2=j2+kw-1; if(b2<0||b2>=19) continue;
          int i2=19*a+b2; int row=i2/20, col=i2%20;
          if(col<10) s+=xt[row*10+col]*h2w[(size_t)c*33+kh*3+kw]; } } }
    { int t=20*j+r; int p=t%19, q=t/19;
      for(int kh=0;kh<3;kh++){ int a=p+kh-1; if(a<0||a>=19) continue;
        for(int kw=0;kw<11;kw++){ int b2=q+kw-5; if(b2<0||b2>=10) continue;
          int i2=19*b2+a; int row=i2/20, col=i2%20;
          if(col<10) s+=xt[col*10+row]*v2w[(size_t)c*33+kh*11+kw]; } } }
    s = bnorm(s,bnp,c,C);
    attv[tid] = 1.f/(1.f+__expf(-s));
  }
  __syncthreads();
  float* dst = xa + ((size_t)(b*DIM+64+c))*LPIX;
  for(int i=tid;i<LPIX;i+=256){
    int y=i/28, x=i%28;
    float a = attv[((y*10)/28)*10 + (x*10)/28];
    dst[i] = xs[i]*a;
  }
}

// qkv: 12 groups x 16 output channels, 2 pixels per thread (8 loads in flight / chunk)
DEV void body_qkv(int blk, int tid, const float* X, const float* w, float* qkvb){
  int og = blk % 12;
  int p0 = (blk/12)*512 + tid;
  if(p0 >= NPIX) return;
  int o0 = og*16;
  int b0 = p0/LPIX, l0 = p0%LPIX;
  int p1 = p0 + 256;
  bool has1 = p1 < NPIX;
  int b1 = has1 ? p1/LPIX : b0, l1 = has1 ? p1%LPIX : l0;
  const float* xp0 = X + ((size_t)(b0*DIM+192))*LPIX + l0;
  const float* xp1 = X + ((size_t)(b1*DIM+192))*LPIX + l1;
  float s0[16], s1[16];
  #pragma unroll
  for(int t=0;t<16;t++){ s0[t]=0.f; s1[t]=0.f; }
  for(int c=0;c<C;c+=4){
    float a0=xp0[(size_t)c*LPIX],     a1=xp0[(size_t)(c+1)*LPIX],
          a2=xp0[(size_t)(c+2)*LPIX], a3=xp0[(size_t)(c+3)*LPIX];
    float e0=xp1[(size_t)c*LPIX],     e1=xp1[(size_t)(c+1)*LPIX],
          e2=xp1[(size_t)(c+2)*LPIX], e3=xp1[(size_t)(c+3)*LPIX];
    #pragma unroll
    for(int t=0;t<16;t++){
      const float* wr = w + (size_t)(o0+t)*C + c;
      float w0=wr[0], w1=wr[1], w2=wr[2], w3=wr[3];
      s0[t] += w0*a0 + w1*a1 + w2*a2 + w3*a3;
      s1[t] += w0*e0 + w1*e1 + w2*e2 + w3*e3;
    }
  }
  int which=o0>>6, head0=(o0&63)>>2;
  #pragma unroll
  for(int t4=0;t4<4;t4++){
    float4* dst = (float4*)(qkvb + (size_t)which*B*NH*LPIX*HD + ((size_t)((b0*NH+head0+t4)*LPIX+l0))*HD);
    *dst = make_float4(s0[4*t4],s0[4*t4+1],s0[4*t4+2],s0[4*t4+3]);
  }
  if(has1){
    #pragma unroll
    for(int t4=0;t4<4;t4++){
      float4* dst = (float4*)(qkvb + (size_t)which*B*NH*LPIX*HD + ((size_t)((b1*NH+head0+t4)*LPIX+l1))*HD);
      *dst = make_float4(s1[4*t4],s1[4*t4+1],s1[4*t4+2],s1[4*t4+3]);
    }
  }
}

// bcdtssd: single 4x784 LDS buffer.
// og<32: conv -> bc2 only.  og>=32: conv into 13 regs -> write back in place ->
// parallel per-wave softmax (plane wv per wave) -> wgt. 3 barriers, no serialization.
DEV void body_bcdtssd(int blk, int tid, float* smem, const float* X, const float* w, const float* dww,
                      float* bc2, float* wgt){
  int b = blk/48, og = blk%48; int o0=og*4;
  float* bc1s = smem;            // 4*784
  const float* xp = X + ((size_t)(b*DIM+128))*LPIX;
  // stage-1: pixels {tid, tid+256, tid+512} fused in one c-loop (12 loads in flight),
  // 16-pixel tail (768..783) by threads 0..15.
  {
    int l0=tid, l1=tid+256, l2=tid+512;
    float acc0[4]={0,0,0,0}, acc1[4]={0,0,0,0}, acc2[4]={0,0,0,0};
    for(int c=0;c<C;c+=4){
      float x00=xp[(size_t)c*LPIX+l0],     x01=xp[(size_t)(c+1)*LPIX+l0],
            x02=xp[(size_t)(c+2)*LPIX+l0], x03=xp[(size_t)(c+3)*LPIX+l0];
      float x10=xp[(size_t)c*LPIX+l1],     x11=xp[(size_t)(c+1)*LPIX+l1],
            x12=xp[(size_t)(c+2)*LPIX+l1], x13=xp[(size_t)(c+3)*LPIX+l1];
      float x20=xp[(size_t)c*LPIX+l2],     x21=xp[(size_t)(c+1)*LPIX+l2],
            x22=xp[(size_t)(c+2)*LPIX+l2], x23=xp[(size_t)(c+3)*LPIX+l2];
      #pragma unroll
      for(int t=0;t<4;t++){
        const float* wr = w + (size_t)(o0+t)*C + c;
        float w0=wr[0], w1=wr[1], w2=wr[2], w3=wr[3];
        acc0[t] += w0*x00 + w1*x01 + w2*x02 + w3*x03;
        acc1[t] += w0*x10 + w1*x11 + w2*x12 + w3*x13;
        acc2[t] += w0*x20 + w1*x21 + w2*x22 + w3*x23;
      }
    }
    #pragma unroll
    for(int t=0;t<4;t++){
      bc1s[t*LPIX+l0]=acc0[t];
      bc1s[t*LPIX+l1]=acc1[t];
      bc1s[t*LPIX+l2]=acc2[t];
    }
    if(tid<16){
      int l=768+tid;
      float a0=0,a1=0,a2=0,a3=0;
      for(int c=0;c<C;c+=4){
        float x0=xp[(size_t)c*LPIX+l],     x1=xp[(size_t)(c+1)*LPIX+l],
              x2=xp[(size_t)(c+2)*LPIX+l], x3=xp[(size_t)(c+3)*LPIX+l];
        const float* w0p = w + (size_t)(o0+0)*C + c;
        const float* w1p = w + (size_t)(o0+1)*C + c;
        const float* w2p = w + (size_t)(o0+2)*C + c;
        const float* w3p = w + (size_t)(o0+3)*C + c;
        a0 += w0p[0]*x0 + w0p[1]*x1 + w0p[2]*x2 + w0p[3]*x3;
        a1 += w1p[0]*x0 + w1p[1]*x1 + w1p[2]*x2 + w1p[3]*x3;
        a2 += w2p[0]*x0 + w2p[1]*x1 + w2p[2]*x2 + w2p[3]*x3;
        a3 += w3p[0]*x0 + w3p[1]*x1 + w3p[2]*x2 + w3p[3]*x3;
      }
      bc1s[0*LPIX+l]=a0; bc1s[1*LPIX+l]=a1; bc1s[2*LPIX+l]=a2; bc1s[3*LPIX+l]=a3;
    }
  }
  __syncthreads();
  if(og < 32){
    // B/C planes: 3x3 depthwise conv, write bc2 only
    for(int i=tid;i<4*LPIX;i+=256){
      int oo=i/LPIX, l=i%LPIX; int y=l/28, x=l%28;
      const float* p = bc1s + oo*LPIX;
      const float* wk = dww + (size_t)(o0+oo)*9;
      float s=0;
      for(int ky=0;ky<3;ky++){ int iy=y+ky-1; if(iy<0||iy>=28) continue;
        for(int kx=0;kx<3;kx++){ int ix=x+kx-1; if(ix<0||ix>=28) continue;
          s += p[iy*28+ix]*wk[ky*3+kx]; } }
      bc2[((size_t)(b*192+o0+oo))*LPIX + l] = s;
    }
  } else {
    // conv into registers (13 per thread), write back in place, parallel softmax
    float cv[13];
    #pragma unroll
    for(int k=0;k<13;k++){
      int i = tid + k*256;
      if(i < 4*LPIX){
        int oo=i/LPIX, l=i%LPIX; int y=l/28, x=l%28;
        const float* p = bc1s + oo*LPIX;
        const float* wk = dww + (size_t)(o0+oo)*9;
        float s=0;
        for(int ky=0;ky<3;ky++){ int iy=y+ky-1; if(iy<0||iy>=28) continue;
          for(int kx=0;kx<3;kx++){ int ix=x+kx-1; if(ix<0||ix>=28) continue;
            s += p[iy*28+ix]*wk[ky*3+kx]; } }
        cv[k]=s;
      }
    }
    __syncthreads();
    #pragma unroll
    for(int k=0;k<13;k++){ int i=tid+k*256; if(i<4*LPIX) bc1s[i]=cv[k]; }
    __syncthreads();
    int wv = tid>>6, lane = tid&63;
    float* row = bc1s + wv*LPIX;
    float mx = -1e30f;
    for(int l=lane;l<LPIX;l+=64) mx = fmaxf(mx, row[l]);
    for(int off=32;off;off>>=1) mx = fmaxf(mx, __shfl_xor(mx,off));
    float sum=0;
    for(int l=lane;l<LPIX;l+=64){ float e=__expf(row[l]-mx); row[l]=e; sum+=e; }
    for(int off=32;off;off>>=1) sum += __shfl_xor(sum,off);
    float inv = 1.f/sum;
    int s_ = o0-128+wv;
    float* wp = wgt + ((size_t)(b*S+s_))*LPIX;
    for(int l=lane;l<LPIX;l+=64) wp[l] = row[l]*inv;
  }
}

// attn: reverted to proven round-4 form (512 blocks, AoS float4 K/V in LDS).
// Round-6 SoA/row-split variant ISSUED MORE VALU (72% busy, 55µs) — reverted.
DEV void body_attn(int blk, int tid, float4* ks, float4* vs, const float* qkvb,
                   float* ob, float* lsb){
  int bh = blk >> 2, ms = blk & 3;
  int b = bh>>4, h = bh&15;
  const float4* q4 = (const float4*)(qkvb + (size_t)bh*LPIX*HD);
  const float4* k4 = (const float4*)(qkvb + (size_t)(B*NH + bh)*LPIX*HD) + ms*196;
  const float4* v4 = (const float4*)(qkvb + (size_t)(2*B*NH + bh)*LPIX*HD) + ms*196;
  for(int i=tid;i<196;i+=256){ ks[i]=k4[i]; vs[i]=v4[i]; }
  __syncthreads();
  const float SC = 0.5f*1.44269504f;
  float* obp = ob + (size_t)ms*B*LPIX*C;
  float* lsq = lsb + (size_t)ms*B*NH*LPIX + (size_t)bh*LPIX;

  float4 q[3];
  #pragma unroll
  for(int j=0;j<3;j++){
    float4 t = q4[tid + 256*j];
    q[j] = make_float4(t.x*SC, t.y*SC, t.z*SC, t.w*SC);
  }
  float l0[3]={0,0,0}, l1[3]={0,0,0};
  float ax0[3]={0,0,0}, ax1[3]={0,0,0};
  float ay0[3]={0,0,0}, ay1[3]={0,0,0};
  float az0[3]={0,0,0}, az1[3]={0,0,0};
  float aw0[3]={0,0,0}, aw1[3]={0,0,0};
  for(int m=0;m<196;m+=2){
    float4 k0=ks[m], k1=ks[m+1];
    float4 v0=vs[m], v1=vs[m+1];
    #pragma unroll
    for(int j=0;j<3;j++){
      float s0 = q[j].x*k0.x + q[j].y*k0.y + q[j].z*k0.z + q[j].w*k0.w;
      float s1 = q[j].x*k1.x + q[j].y*k1.y + q[j].z*k1.z + q[j].w*k1.w;
      float p0 = __builtin_amdgcn_exp2f(s0);
      float p1 = __builtin_amdgcn_exp2f(s1);
      l0[j]+=p0;        l1[j]+=p1;
      ax0[j]+=p0*v0.x;  ax1[j]+=p1*v1.x;
      ay0[j]+=p0*v0.y;  ay1[j]+=p1*v1.y;
      az0[j]+=p0*v0.z;  az1[j]+=p1*v1.z;
      aw0[j]+=p0*v0.w;  aw1[j]+=p1*v1.w;
    }
  }
  #pragma unroll
  for(int j=0;j<3;j++){
    int r = tid + 256*j;
    *(float4*)(obp + ((size_t)(b*LPIX+r))*C + h*4) =
        make_float4(ax0[j]+ax1[j], ay0[j]+ay1[j], az0[j]+az1[j], aw0[j]+aw1[j]);
    lsq[r] = l0[j]+l1[j];
  }
  if(tid < 16){
    int r = 768 + tid;
    float4 t = q4[r];
    float4 qq = make_float4(t.x*SC,t.y*SC,t.z*SC,t.w*SC);
    float ls=0; float4 a=make_float4(0,0,0,0);
    for(int m=0;m<196;m++){
      float4 kv=ks[m], vv=vs[m];
      float sc = qq.x*kv.x+qq.y*kv.y+qq.z*kv.z+qq.w*kv.w;
      float p = __builtin_amdgcn_exp2f(sc);
      ls+=p; a.x+=p*vv.x; a.y+=p*vv.y; a.z+=p*vv.z; a.w+=p*vv.w;
    }
    *(float4*)(obp + ((size_t)(b*LPIX+r))*C + h*4) = a;
    lsq[r] = ls;
  }
}

DEV void body_star(int blk, int tid, const float* x1o, const float* f1w,const float* f1b,const float* f2w,const float* f2b,float* t1){
  int jg, b, l; if(!upix(blk, tid, 32, jg, b, l)) return;
  int j0=jg*4;
  const float* xp = x1o + (size_t)b*C*LPIX + l;
  float a[4], g[4];
  for(int t=0;t<4;t++){ a[t]=f1b[j0+t]; g[t]=f2b[j0+t]; }
  for(int c=0;c<C;c+=4){
    float x0=xp[(size_t)c*LPIX],     x1=xp[(size_t)(c+1)*LPIX],
          x2=xp[(size_t)(c+2)*LPIX], x3=xp[(size_t)(c+3)*LPIX];
    #pragma unroll
    for(int t=0;t<4;t++){
      const float* f1r = f1w + (size_t)(j0+t)*C + c;
      const float* f2r = f2w + (size_t)(j0+t)*C + c;
      a[t] += f1r[0]*x0 + f1r[1]*x1 + f1r[2]*x2 + f1r[3]*x3;
      g[t] += f2r[0]*x0 + f2r[1]*x1 + f2r[2]*x2 + f2r[3]*x3;
    }
  }
  for(int t=0;t<4;t++){
    float av = fminf(fmaxf(a[t],0.f),6.f);
    t1[((size_t)(b*HID+j0+t))*LPIX + l] = av*g[t];
  }
}

// gproj: ngroups=4, 16 output channels per thread.
DEV void body_gproj(int blk, int tid, const float* t1, const float* gw,const float* gb,const float* bnp,float* t2){
  int cg, b, l; if(!upix(blk, tid, 4, cg, b, l)) return;
  int c0=cg*16;
  const float* tp = t1 + (size_t)b*HID*LPIX + l;
  float s[16];
  #pragma unroll
  for(int t=0;t<16;t++) s[t]=gb[c0+t];
  for(int j=0;j<HID;j++){
    float xv = tp[(size_t)j*LPIX];
    #pragma unroll
    for(int t=0;t<16;t++) s[t]+=gw[(size_t)(c0+t)*HID+j]*xv;
  }
  #pragma unroll
  for(int t=0;t<16;t++) t2[((size_t)(b*C+c0+t))*LPIX + l]=bnorm(s[t],bnp,c0+t,C);
}

// x4: ngroups=4, 16 output channels per thread; ob partials read as float4.
DEV void body_x4(int blk, int tid, const float* X, const float* ob, const float* lsb,
                 const float* projw, const float* bnp, float* xa){
  int cg, b, l; if(!upix(blk, tid, 4, cg, b, l)) return;
  int c0=cg*16;
  const float* p0 = ob + ((size_t)(b*LPIX+l))*C;
  const float* p1 = p0 + (size_t)B*LPIX*C;
  const float* p2 = p1 + (size_t)B*LPIX*C;
  const float* p3 = p2 + (size_t)B*LPIX*C;
  float s[16];
  #pragma unroll
  for(int t=0;t<16;t++) s[t]=0.f;
  for(int h=0;h<NH;h++){
    size_t li = ((size_t)(b*NH+h))*LPIX + l;
    float lsum = lsb[li] + lsb[(size_t)B*NH*LPIX+li] + lsb[(size_t)2*B*NH*LPIX+li] + lsb[(size_t)3*B*NH*LPIX+li];
    float iv = 1.f/lsum;
    float4 q0=*(const float4*)(p0+h*4), q1=*(const float4*)(p1+h*4),
           q2=*(const float4*)(p2+h*4), q3=*(const float4*)(p3+h*4);
    float ov0=(q0.x+q1.x+q2.x+q3.x)*iv;
    float ov1=(q0.y+q1.y+q2.y+q3.y)*iv;
    float ov2=(q0.z+q1.z+q2.z+q3.z)*iv;
    float ov3=(q0.w+q1.w+q2.w+q3.w)*iv;
    const float* pw = projw + h*4;
    #pragma unroll
    for(int t=0;t<16;t++){
      const float* pr = pw + (size_t)(c0+t)*C;
      s[t] += pr[0]*ov0 + pr[1]*ov1 + pr[2]*ov2 + pr[3]*ov3;
    }
  }
  #pragma unroll
  for(int t=0;t<16;t++){
    float v = s[t] + X[((size_t)(b*DIM+192+c0+t))*LPIX + l];
    xa[((size_t)(b*DIM+192+c0+t))*LPIX + l] = bnorm(v,bnp,c0+t,C);
  }
}

// h: l-tile split into 2x98 halves -> LDS 2*16*99 floats (12.7KB)
DEV void body_h(int blk, int tid, float* smem, const float* X, const float* wgt, const float* bc2, float* hq){
  int b = blk >> 6, sub = blk & 63;
  int tile = sub >> 2, qq = sub & 3;
  int ct = (tile>>2)*16, st = (tile&3)*16;
  float (*Xs)[99] = (float(*)[99])smem;
  float (*Ws)[99] = (float(*)[99])(smem + 16*99);
  int tc = tid>>4, ts = tid&15;
  float acc=0;
  #pragma unroll
  for(int half=0;half<2;half++){
    int lb = qq*196 + half*98;
    for(int i=tid;i<16*98;i+=256){
      int r=i/98, col=i%98;
      Xs[r][col] = X[((size_t)(b*DIM+128+ct+r))*LPIX + lb + col];
      Ws[r][col] = wgt[((size_t)(b*S+st+r))*LPIX + lb + col]
                 * bc2[((size_t)(b*192+st+r))*LPIX + lb + col];
    }
    __syncthreads();
    #pragma unroll 7
    for(int l=0;l<98;l++) acc += Xs[tc][l]*Ws[ts][l];
    __syncthreads();
  }
  hq[(size_t)qq*B*C*S + ((size_t)(b*C+ct+tc))*S + st+ts] = acc;
}

// dw2t: zero-padded 34x34 LDS tile, straight-line 7x7 conv
DEV void body_dw2t(int bc, int tid, float* xs, const float* t2, const float* w, const float* bias, float* xa){
  int c = bc & 63, b = bc >> 6;
  const float* tp = t2 + ((size_t)(b*C+c))*LPIX;
  for(int i=tid;i<34*34;i+=256) xs[i]=0.f;
  __syncthreads();
  for(int i=tid;i<LPIX;i+=256){ int y=i/28, x=i%28; xs[(y+3)*34+(x+3)]=tp[i]; }
  __syncthreads();
  const float* wc = w + (size_t)c*49;
  float bs = bias[c];
  for(int i=tid;i<LPIX;i+=256){
    int y=i/28, x=i%28;
    float s = bs;
    #pragma unroll
    for(int ky=0;ky<7;ky++){
      #pragma unroll
      for(int kx=0;kx<7;kx++)
        s += xs[(y+ky)*34 + x+kx]*wc[ky*7+kx];
    }
    xa[((size_t)(b*DIM+c))*LPIX + i] = s;
  }
}

DEV void body_mixho(int blk, int tid, float* smem, const float* hq, const float* hzw,
                    const float* Dp, const float* outw, float* ho){
  int b = blk >> 3, st = (blk & 7) * 8;
  float (*hs2)[8] = (float(*)[8])smem;
  float (*g1s)[8] = (float(*)[8])(smem + C*8);
  for(int i=tid;i<C*8;i+=256){
    int k=i>>3, si=i&7;
    size_t off = ((size_t)(b*C+k))*S + st + si;
    hs2[k][si] = hq[off] + hq[(size_t)B*C*S+off] + hq[(size_t)2*B*C*S+off] + hq[(size_t)3*B*C*S+off];
  }
  __syncthreads();
  float D = Dp[0];
  for(int i=tid;i<C*8;i+=256){
    int c=i>>3, si=i&7;
    float hv=0, zv=0;
    for(int k=0;k<C;k++){ float x=hs2[k][si]; hv+=hzw[(size_t)c*C+k]*x; zv+=hzw[(size_t)(C+c)*C+k]*x; }
    float sil = zv/(1.f+__expf(-zv));
    g1s[c][si]=hv*sil+hv*D;
  }
  __syncthreads();
  for(int i=tid;i<C*8;i+=256){
    int c=i>>3, si=i&7;
    float acc=0;
    for(int k=0;k<C;k++) acc+=outw[(size_t)c*C+k]*g1s[k][si];
    ho[((size_t)(b*C+c))*S + st + si]=acc;
  }
}

// x3: 8 groups x 8 outputs (200 blocks, co-scheduled with 512 dw2t); s-loop batched x2
DEV void body_x3(int blk, int tid, const float* ho, const float* bc2, float* xa){
  int cg, b, l; if(!upix(blk, tid, 8, cg, b, l)) return;
  int c0=cg*8;
  const float* hp = ho + (size_t)(b*C+c0)*S;
  const float* cm = bc2 + ((size_t)(b*192+64))*LPIX + l;
  float s[8];
  #pragma unroll
  for(int t=0;t<8;t++) s[t]=0.f;
  for(int s_=0;s_<S;s_+=2){
    float cv0 = cm[(size_t)s_*LPIX];
    float cv1 = cm[(size_t)(s_+1)*LPIX];
    #pragma unroll
    for(int t=0;t<8;t++)
      s[t] += hp[(size_t)t*S+s_]*cv0 + hp[(size_t)t*S+s_+1]*cv1;
  }
  #pragma unroll
  for(int t=0;t<8;t++)
    xa[((size_t)(b*DIM+128+c0+t))*LPIX + l] = s[t];
}

// ================= stage kernels =================
// S1: [0,384)=bcdtssd+softmax  [384,896)=branch2  [896,896+QB)=qkv  [..,..+512)=dw1t
__global__ void k_s1(const float* X,
                     const float* bcdt_w, const float* ssd_dw, float* bc2, float* wgt,
                     const float* h1w,const float* v1w,const float* h2w,const float* v2w,const float* bn_mra,
                     const float* qkv_w, float* qkvb,
                     const float* dw1_w,const float* dw1_b,const float* bn_dw1,
                     float* xa, float* x1o){
  __shared__ float smem[4*LPIX];
  int blk = blockIdx.x, tid = threadIdx.x;
  if(blk < 384)            body_bcdtssd(blk, tid, smem, X, bcdt_w, ssd_dw, bc2, wgt);
  else if(blk < 896)       body_branch2(blk-384, tid, smem, X, h1w,v1w,h2w,v2w, bn_mra, xa);
  else if(blk < 896+QB)    body_qkv(blk-896, tid, X, qkv_w, qkvb);
  else                     body_dw1t(blk-(896+QB), tid, smem, X, dw1_w, dw1_b, bn_dw1, x1o);
}

// S2: [0,512)=attn  [512,512+32*CH)=star  [..,..+512)=h   (LDS 792 float4 = 12.7KB)
__global__ void k_s2(const float* qkvb, float* ob, float* lsb,
                     const float* x1o, const float* f1w,const float* f1b,const float* f2w,const float* f2b, float* t1,
                     const float* X, const float* wgt, const float* bc2, float* hq){
  __shared__ float4 smem4[792];
  float* smem = (float*)smem4;
  int blk = blockIdx.x, tid = threadIdx.x;
  if(blk < 512)            body_attn(blk, tid, smem4, smem4+196, qkvb, ob, lsb);
  else if(blk < 512+32*CH) body_star(blk-512, tid, x1o, f1w,f1b,f2w,f2b, t1);
  else                     body_h(blk-(512+32*CH), tid, smem, X, wgt, bc2, hq);
}

// S3: [0,64)=mixho  [64,64+4*CH)=gproj  [64+4*CH,64+8*CH)=x4
__global__ void k_s3(const float* t1, const float* gw,const float* gb,const float* bn_g, float* t2,
                     const float* X, const float* ob, const float* lsb,
                     const float* projw, const float* bn_n4, float* xa,
                     const float* hq, const float* hzw, const float* Dp, const float* outw, float* ho){
  __shared__ float smem[2*C*8];
  int blk = blockIdx.x, tid = threadIdx.x;
  if(blk < 64)           body_mixho(blk, tid, smem, hq, hzw, Dp, outw, ho);
  else if(blk < 64+4*CH) body_gproj(blk-64, tid, t1, gw, gb, bn_g, t2);
  else                   body_x4(blk-(64+4*CH), tid, X, ob, lsb, projw, bn_n4, xa);
}

// S4: [0,512)=dw2t  [512,512+8*CH)=x3
__global__ void k_s4(const float* t2, const float* dw2_w, const float* dw2_b, float* xa,
                     const float* ho, const float* bc2){
  __shared__ float smem[34*34];
  int blk = blockIdx.x, tid = threadIdx.x;
  if(blk < 512) body_dw2t(blk, tid, smem, t2, dw2_w, dw2_b, xa);
  else          body_x3(blk-512, tid, ho, bc2, xa);
}

// mid: 32 groups x 4 outputs (800 blocks), c-loop batched x4 (4 loads in flight)
__global__ void k_mid(const float* xa, const float* m1w, const float* bnp, float* mid){
  int jg, b, l; if(!upix(blockIdx.x, threadIdx.x, 32, jg, b, l)) return;
  int j0=jg*4;
  const float* xp = xa + (size_t)b*DIM*LPIX + l;
  float s[4]={0,0,0,0};
  for(int c=0;c<DIM;c+=4){
    float x0=xp[(size_t)c*LPIX],     x1=xp[(size_t)(c+1)*LPIX],
          x2=xp[(size_t)(c+2)*LPIX], x3=xp[(size_t)(c+3)*LPIX];
    #pragma unroll
    for(int t=0;t<4;t++){
      const float* wr = m1w + (size_t)(j0+t)*DIM + c;
      s[t] += wr[0]*x0 + wr[1]*x1 + wr[2]*x2 + wr[3]*x3;
    }
  }
  for(int t=0;t<4;t++)
    mid[((size_t)(b*HID+j0+t))*LPIX + l] = fmaxf(bnorm(s[t],bnp,j0+t,HID),0.f);
}

// out: 32 groups x 8 outputs (800 blocks), j-loop batched x4
__global__ void k_out(const float* X, const float* mid, const float* m2w, const float* bnp, float* out){
  int cg, b, l; if(!upix(blockIdx.x, threadIdx.x, 32, cg, b, l)) return;
  int c0=cg*8;
  const float* mp_ = mid + (size_t)b*HID*LPIX + l;
  float s[8]={0,0,0,0,0,0,0,0};
  for(int j=0;j<HID;j+=4){
    float m0=mp_[(size_t)j*LPIX],     m1=mp_[(size_t)(j+1)*LPIX],
          m2=mp_[(size_t)(j+2)*LPIX], m3=mp_[(size_t)(j+3)*LPIX];
    #pragma unroll
    for(int t=0;t<8;t++){
      const float* wr = m2w + (size_t)(c0+t)*HID + j;
      s[t] += wr[0]*m0 + wr[1]*m1 + wr[2]*m2 + wr[3]*m3;
    }
  }
  for(int t=0;t<8;t++){
    size_t oi = ((size_t)(b*DIM+c0+t))*LPIX + l;
    out[oi] = bnorm(s[t],bnp,c0+t,DIM) + X[oi];
  }
}

extern "C" void kernel_launch(void* const* d_in, const int* in_sizes, int n_in,
                              void* d_out, int out_size, void* d_ws, size_t ws_size,
                              hipStream_t stream) {
  const float* X      = (const float*)d_in[0];
  const float* dw1_w  = (const float*)d_in[1];
  const float* dw1_b  = (const float*)d_in[2];
  const float* bn_dw1 = (const float*)d_in[3];
  const float* f1_w   = (const float*)d_in[4];
  const float* f1_b   = (const float*)d_in[5];
  const float* f2_w   = (const float*)d_in[6];
  const float* f2_b   = (const float*)d_in[7];
  const float* g_w    = (const float*)d_in[8];
  const float* g_b    = (const float*)d_in[9];
  const float* bn_g   = (const float*)d_in[10];
  const float* dw2_w  = (const float*)d_in[11];
  const float* dw2_b  = (const float*)d_in[12];
  const float* hatt1w = (const float*)d_in[13];
  const float* vatt1w = (const float*)d_in[14];
  const float* hatt2w = (const float*)d_in[15];
  const float* vatt2w = (const float*)d_in[16];
  const float* bn_mra = (const float*)d_in[17];
  const float* bcdt_w = (const float*)d_in[18];
  const float* ssd_dw = (const float*)d_in[19];
  const float* hz_w   = (const float*)d_in[20];
  const float* out_w  = (const float*)d_in[21];
  const float* D_p    = (const float*)d_in[23];
  const float* qkv_w  = (const float*)d_in[24];
  const float* proj_w = (const float*)d_in[25];
  const float* bn_n4  = (const float*)d_in[26];
  const float* mlp1_w = (const float*)d_in[27];
  const float* bn_mlp = (const float*)d_in[28];
  const float* mlp2_w = (const float*)d_in[29];
  const float* bn_n1  = (const float*)d_in[30];

  float* ws   = (float*)d_ws;
  float* x1o  = ws+OFF_X1O;  float* t1  = ws+OFF_T1;  float* t2  = ws+OFF_T2;
  float* xa   = ws+OFF_XA;   float* bc2 = ws+OFF_BC2; float* wgt = ws+OFF_WGT;
  float* hq   = ws+OFF_H;    float* ho  = ws+OFF_HO;  float* qkvb= ws+OFF_QKV;
  float* ob   = ws+OFF_O;    float* lsb = ws+OFF_LS;  float* mid = ws+OFF_MID;

  dim3 blk(256);

  k_s1 <<<dim3(896+QB+512),blk,0,stream>>>(X, bcdt_w, ssd_dw, bc2, wgt,
                                     hatt1w,vatt1w,hatt2w,vatt2w,bn_mra,
                                     qkv_w, qkvb, dw1_w,dw1_b,bn_dw1, xa, x1o);
  k_s2 <<<dim3(512+32*CH+512),blk,0,stream>>>(qkvb, ob, lsb,
                                     x1o, f1_w,f1_b,f2_w,f2_b, t1,
                                     X, wgt, bc2, hq);
  k_s3 <<<dim3(64+8*CH),blk,0,stream>>>(t1, g_w,g_b,bn_g, t2,
                                     X, ob, lsb, proj_w, bn_n4, xa,
                                     hq, hz_w, D_p, out_w, ho);
  k_s4 <<<dim3(512+8*CH),blk,0,stream>>>(t2, dw2_w, dw2_b, xa, ho, bc2);
  k_mid<<<dim3(32*CH),blk,0,stream>>>(xa,mlp1_w,bn_mlp,mid);
  k_out<<<dim3(32*CH),blk,0,stream>>>(X,mid,mlp2_w,bn_n1,(float*)d_out);
}